// Round 14
// baseline (286.738 us; speedup 1.0000x reference)
//
#include <hip/hip_runtime.h>
#include <hip/hip_bf16.h>
#include <stdint.h>

// ---------------------------------------------------------------------------
// TensorizedGRU: m[b,l] = sum_{j,k} s[b,j] x[b,k] W[l,j,k]  (l in [0,256): W1||W2)
// R14 = R13 depth-4 prefetch, UNCLAMPED (+ coalesced LDS-transpose W producer).
//  - gemm: __launch_bounds__(256,1): R13's (256,2) made the allocator clamp
//    to 128 VGPR and spill buf[] to scratch (WRITE_SIZE 33->44.5MB). Grid 512
//    still co-resides 2 blocks/CU while VGPR <= 256.
//  - depth-4 circular register prefetch: ~3 chunks (~1860cyc) of B in flight
//    vs ~1500-2000cyc loaded-L2 latency; vmcnt never drains.
//  - prep W: block does 16-row x 512-K f32 slab: coalesced float4 loads ->
//    LDS [16][516] -> emit 16 consecutive 1KB fragments, coalesced stores.
//    (was: 16-line gather reads, ~45-55us; now both sides streaming.)
// ws layout:
//   Wt   bf16 [256][65536]  @ 0          (33,554,432 B)  frag-ordered
//   x_bf bf16 [4096][256]   @ 32MiB+2MiB ( 2,097,152 B)
//   Mpart f32 [8][4096][256]@ +2MiB      (33,554,432 B)
// ---------------------------------------------------------------------------

typedef short bf8 __attribute__((ext_vector_type(8)));   // 8 bf16 = 4 VGPRs
typedef float f32x4 __attribute__((ext_vector_type(4)));

static constexpr size_t WT_OFF  = 0;
static constexpr size_t XBF_OFF = 33554432 + 2097152;
static constexpr size_t MP_OFF  = XBF_OFF + 2097152;

// round-to-nearest-even f32 -> bf16 (finite inputs only)
__device__ __forceinline__ unsigned f2bf(float f) {
    unsigned u = __builtin_bit_cast(unsigned, f);
    return (u + 0x7fffu + ((u >> 16) & 1u)) >> 16;
}
__device__ __forceinline__ unsigned pack2bf(float a, float b) {
    return f2bf(a) | (f2bf(b) << 16);
}

// ---------------- prep: coalesced slab->frag W producer + x cast ------------
// bx < 2048: W slab (n16 = bx>>7, K0 = (bx&127)*512): load 16x512 f32
//   coalesced into LDS, emit frags F = ((n16*1024 + K0/64 + kc)*2 + kst),
//   16 consecutive 1KB fragments = 16KB contiguous, coalesced.
// bx in [2048, 3072): x = in0||in1 -> bf16.
__global__ void prep_wx(const float* __restrict__ W1, const float* __restrict__ W2,
                        const float* __restrict__ in0, const float* __restrict__ in1,
                        uint4* __restrict__ Wt, unsigned* __restrict__ x_bf) {
    int bx = blockIdx.x;
    if (bx < 2048) {
        const int t = threadIdx.x;
        const int n16 = bx >> 7;
        const int K0 = (bx & 127) * 512;
        __shared__ float Lt[16][516];
        #pragma unroll
        for (int i = 0; i < 8; ++i) {
            int idx = i * 256 + t;
            int row = idx >> 7;                  // 0..15
            int c4 = (idx & 127) * 4;
            int n = n16 * 16 + row;
            const float* src = (n < 128 ? W1 + ((size_t)n << 16)
                                        : W2 + ((size_t)(n - 128) << 16)) + K0 + c4;
            float4 v = *(const float4*)src;
            Lt[row][c4 + 0] = v.x; Lt[row][c4 + 1] = v.y;
            Lt[row][c4 + 2] = v.z; Lt[row][c4 + 3] = v.w;
        }
        __syncthreads();
        #pragma unroll
        for (int u4 = 0; u4 < 4; ++u4) {
            int u = u4 * 256 + t;                // 0..1023
            int fi = u >> 6;                     // 0..15 local frag
            int l = u & 63;                      // lane slot
            int kc = fi >> 1, kst = fi & 1;
            int row = l & 15;
            int kloc = kc * 64 + kst * 32 + (l >> 4) * 8;
            const float* p = &Lt[row][kloc];
            uint4 o;
            o.x = pack2bf(p[0], p[1]); o.y = pack2bf(p[2], p[3]);
            o.z = pack2bf(p[4], p[5]); o.w = pack2bf(p[6], p[7]);
            size_t F = ((size_t)n16 * 1024 + (K0 >> 6) + kc) * 2 + kst;
            Wt[F * 64 + l] = o;
        }
    } else {
        unsigned v = (bx - 2048) * 256 + threadIdx.x; // 262,144 units of 4 elems
        unsigned b = v >> 6;
        unsigned j4 = (v & 63u) * 4u;
        const float* src = (j4 < 128) ? (in0 + (size_t)b * 128 + j4)
                                      : (in1 + (size_t)b * 128 + (j4 - 128));
        float4 a = *(const float4*)src;
        uint2 o;
        o.x = pack2bf(a.x, a.y);
        o.y = pack2bf(a.z, a.w);
        ((uint2*)x_bf)[v] = o;
    }
}

// ---------------- main GEMM: 128x128 tile, split-K=8, depth-4 prefetch ------
// grid 512: ks = bx&7 (XCD-pinned), nt = (bx>>3)&1, mt = bx>>4 (0..31).
// block 256 = 4 waves; wave w owns n-cols [w*32, w*32+32), all 128 m-rows.
__launch_bounds__(256, 1)
__global__ void gemm_p(const unsigned char* __restrict__ Wt,
                       const float* __restrict__ st0, const float* __restrict__ st1,
                       const __hip_bfloat16* __restrict__ x_bf,
                       float* __restrict__ Mpart) {
    const int bx = blockIdx.x;
    const int ks = bx & 7;                  // split-K slice, pinned per XCD
    const int nt = (bx >> 3) & 1;
    const int mt = bx >> 4;
    const int b0 = mt << 7, n0 = nt << 7;
    const int tid  = threadIdx.x;
    const int lane = tid & 63, wave = tid >> 6;
    const int l15 = lane & 15, l4 = lane >> 4;

    // s tile: [32 j][132 r] f32 (pad to 132 -> broadcast-clean)
    __shared__ __align__(16) float Sl[32 * 132];
    for (int idx = tid; idx < 4096; idx += 256) {
        int r = idx >> 5, j = idx & 31;
        int jg = ks * 32 + j;
        float v = (jg < 128) ? st0[(size_t)(b0 + r) * 128 + jg]
                             : st1[(size_t)(b0 + r) * 128 + (jg - 128)];
        Sl[j * 132 + r] = v;
    }
    __syncthreads();                        // the ONLY barrier

    // B-frag bases, fragment-ordered Wt:
    // n16(nf) = nt*8 + wave*2 + nf; frag addr = ((n16*1024 + kchunk)*2+kst)*1024 + lane*16
    const unsigned char* rbn[2];
    #pragma unroll
    for (int nf = 0; nf < 2; ++nf)
        rbn[nf] = Wt + ((size_t)(nt * 8 + wave * 2 + nf) << 21) + lane * 16;
    const float* sB = Sl + l4 * 4;

    f32x4 racc[8][2];
    #pragma unroll
    for (int mf = 0; mf < 8; ++mf)
        #pragma unroll
        for (int nf = 0; nf < 2; ++nf)
            racc[mf][nf] = (f32x4){0.f, 0.f, 0.f, 0.f};
    const f32x4 zacc = (f32x4){0.f, 0.f, 0.f, 0.f};

    // chunk c in [0,128): q = c>>5 (x-quadrant), j = c&31 (local j)
    // kchunk(c) = ((ks*32 + j)*4 + q); byte offset = kchunk*2048 (+ kst*1024)
    auto kof = [&](int c) { return (size_t)(((ks * 32 + (c & 31)) * 4 + (c >> 5)) * 2048); };

    // depth-4 circular B prefetch: buf[d] holds chunk (c with c&3 == d)
    bf8 buf[4][2][2];                       // [slot][nf][kst]
    #pragma unroll
    for (int d = 0; d < 3; ++d) {           // prime slots 0..2 with chunks 0..2
        const size_t kd = kof(d);
        #pragma unroll
        for (int nf = 0; nf < 2; ++nf)
            #pragma unroll
            for (int kst = 0; kst < 2; ++kst)
                buf[d][nf][kst] = *(const bf8*)(rbn[nf] + kd + kst * 1024);
    }

    bf8 a[8][2];                            // x A-frags, reloaded at q boundary

    for (int cb = 0; cb < 128; cb += 4) {
        #pragma unroll
        for (int u = 0; u < 4; ++u) {
            const int c = cb + u;
            const int pp = c & 3;
            const int q = c >> 5, j = c & 31;
            if (j == 0) {                   // new x-quadrant: reload A-frags
                const __hip_bfloat16* xb = x_bf + q * 64 + l4 * 8;
                #pragma unroll
                for (int mf = 0; mf < 8; ++mf)
                    #pragma unroll
                    for (int kst = 0; kst < 2; ++kst)
                        a[mf][kst] = *(const bf8*)(xb + (size_t)(b0 + mf * 16 + l15) * 256 + kst * 32);
            }
            // prefetch chunk c+3 into slot (c+3)&3 (wrap harmless)
            {
                const size_t k3 = kof((c + 3) & 127);
                const int p3 = (c + 3) & 3;
                #pragma unroll
                for (int nf = 0; nf < 2; ++nf)
                    #pragma unroll
                    for (int kst = 0; kst < 2; ++kst)
                        buf[p3][nf][kst] = *(const bf8*)(rbn[nf] + k3 + kst * 1024);
            }
            // s broadcast values for this j
            f32x4 sv[8];
            #pragma unroll
            for (int mf = 0; mf < 8; ++mf)
                sv[mf] = *(const f32x4*)(sB + j * 132 + mf * 16);
            // 32 MFMA + f32 scale-accumulate
            #pragma unroll
            for (int nf = 0; nf < 2; ++nf) {
                bf8 bf0 = buf[pp][nf][0];
                bf8 bf1 = buf[pp][nf][1];
                #pragma unroll
                for (int mf = 0; mf < 8; ++mf) {
                    f32x4 m0 = __builtin_amdgcn_mfma_f32_16x16x32_bf16(a[mf][0], bf0, zacc, 0, 0, 0);
                    m0 = __builtin_amdgcn_mfma_f32_16x16x32_bf16(a[mf][1], bf1, m0, 0, 0, 0);
                    racc[mf][nf] += sv[mf] * m0;
                }
            }
        }
    }

    // split-K partial stores (regular stores: producer->consumer coherence)
    float* mp = Mpart + ((size_t)ks << 20);
    #pragma unroll
    for (int mf = 0; mf < 8; ++mf)
        #pragma unroll
        for (int nf = 0; nf < 2; ++nf) {
            int b = b0 + mf * 16 + l4 * 4;
            int n = n0 + wave * 32 + nf * 16 + l15;
            #pragma unroll
            for (int r = 0; r < 4; ++r)
                mp[(size_t)(b + r) * 256 + n] = racc[mf][nf][r];
        }
}

// ---------------- epilogue: reduce split-K, s@W3, activations, blend --------
__global__ void epilogue(const float* __restrict__ st0, const float* __restrict__ st1,
                         const float* __restrict__ b1, const float* __restrict__ b2,
                         const float* __restrict__ W3, const float* __restrict__ Mpart,
                         float* __restrict__ out) {
    const int tid = threadIdx.x;
    const int h = tid & 127, rg = tid >> 7;          // rg in {0,1}
    const int bbase = blockIdx.x * 8;                // 8 rows per block
    __shared__ float srow[8][256];
    #pragma unroll
    for (int i = 0; i < 8; ++i) {
        int idx = i * 256 + tid;
        int r = idx >> 8, j = idx & 255;
        float v = (j < 128) ? st0[(size_t)(bbase + r) * 128 + j]
                            : st1[(size_t)(bbase + r) * 128 + (j - 128)];
        srow[r][j] = v;
    }
    __syncthreads();
    float acc0 = 0.f, acc1 = 0.f, acc2 = 0.f, acc3 = 0.f;
    for (int j = 0; j < 256; ++j) {
        float w = W3[j * 128 + h];
        acc0 += srow[rg][j] * w;
        acc1 += srow[rg + 2][j] * w;
        acc2 += srow[rg + 4][j] * w;
        acc3 += srow[rg + 6][j] * w;
    }
    float accs[4] = {acc0, acc1, acc2, acc3};
    float bb1 = b1[h], bb2 = b2[h];
    #pragma unroll
    for (int i = 0; i < 4; ++i) {
        int b = bbase + rg + i * 2;
        float m1 = 0.f, m2 = 0.f;
        #pragma unroll
        for (int k = 0; k < 8; ++k) {
            m1 += Mpart[((size_t)k << 20) + (size_t)b * 256 + h];
            m2 += Mpart[((size_t)k << 20) + (size_t)b * 256 + 128 + h];
        }
        float u = 1.0f / (1.0f + expf(-(m2 + bb2)));
        float t = tanhf(m1 + bb1);
        out[(size_t)b * 128 + h] = u * t + (1.0f - u) * accs[i];
    }
}

extern "C" void kernel_launch(void* const* d_in, const int* in_sizes, int n_in,
                              void* d_out, int out_size, void* d_ws, size_t ws_size,
                              hipStream_t stream) {
    const float* in0 = (const float*)d_in[0];
    const float* in1 = (const float*)d_in[1];
    const float* st0 = (const float*)d_in[2];
    const float* st1 = (const float*)d_in[3];
    const float* W1  = (const float*)d_in[4];
    const float* b1  = (const float*)d_in[5];
    const float* W2  = (const float*)d_in[6];
    const float* b2  = (const float*)d_in[7];
    const float* W3  = (const float*)d_in[8];
    float* out = (float*)d_out;
    char* ws = (char*)d_ws;

    unsigned char* Wt   = (unsigned char*)(ws + WT_OFF);
    unsigned*      x_bf = (unsigned*)(ws + XBF_OFF);
    float*         Mp   = (float*)(ws + MP_OFF);

    prep_wx<<<3072, 256, 0, stream>>>(W1, W2, in0, in1, (uint4*)Wt, x_bf);
    gemm_p<<<512, 256, 0, stream>>>(Wt, st0, st1, (const __hip_bfloat16*)x_bf, Mp);
    epilogue<<<512, 256, 0, stream>>>(st0, st1, b1, b2, W3, Mp, out);
}